// Round 5
// baseline (96.198 us; speedup 1.0000x reference)
//
#include <hip/hip_runtime.h>
#include <hip/hip_bf16.h>
#include <stdint.h>

// LinearEnsemble: out[b,m,o] = sum_i W[m,o,i]*x[b,i] + bias[m,o]
// == C[4096x8192] = x[4096x1024] * Wbig^T (+bias), Wbig = [8192x1024] row-major.
// v6: 32x32x16 MFMA reshape of the ring-4 pipeline.
//   - per wave per K=32 slice: 12 ds_read_b128 (same bytes as v5) but only
//     16 MFMA (32x32x16, faster rate) and TWO counted lgkm waits:
//     issue 12 reads -> lgkmcnt(6) -> 8 MFMA(ks0) -> lgkmcnt(0) -> 8 MFMA(ks1).
//     ks1 frags land under the ks0 MFMA block (pipe overlap, no wait-all).
//   - all LDS addresses are base-pointer + compile-time offset (slot stride in
//     the imm) -> no VALU addr work in the steady loop.
//   - granule involution swizzle (conflict-free, verified R2), counted VMCNT(8)
//     staging guard w/ taper, 1 barrier/slice, setprio, XCD banding: unchanged.

typedef __bf16 bf16;
typedef __attribute__((ext_vector_type(8))) __bf16 bf16x8;
typedef __attribute__((ext_vector_type(4))) float f32x4;
typedef __attribute__((ext_vector_type(16))) float f32x16;

#define GAS __attribute__((address_space(1)))
#define LAS __attribute__((address_space(3)))

__device__ __forceinline__ void gload_lds16(void* lds, const void* g) {
    __builtin_amdgcn_global_load_lds((const GAS uint32_t*)g, (LAS uint32_t*)lds, 16, 0, 0);
}

// raw barrier with compiler-level memory fence (no vmcnt/lgkm drain emitted)
__device__ __forceinline__ void wg_barrier() {
    asm volatile("" ::: "memory");
    __builtin_amdgcn_s_barrier();
    asm volatile("" ::: "memory");
}

#define VMCNT(n)   asm volatile("s_waitcnt vmcnt(" #n ")" ::: "memory")
#define LGKMCNT(n) asm volatile("s_waitcnt lgkmcnt(" #n ")" ::: "memory")
#define SCHED_FENCE() __builtin_amdgcn_sched_barrier(0)

// untracked LDS fragment read; ordering enforced by waits + SCHED_FENCE (rule 18)
template<int OFF>
__device__ __forceinline__ bf16x8 ds_read_frag(const char* p) {
    f32x4 r;
    asm volatile("ds_read_b128 %0, %1 offset:%2"
                 : "=v"(r)
                 : "v"((const LAS char*)p), "i"(OFF));
    return __builtin_bit_cast(bf16x8, r);
}

#define MFMA32(A, B, C) __builtin_amdgcn_mfma_f32_32x32x16_bf16(A, B, C, 0, 0, 0)

__device__ __forceinline__ uint4 pack8(float4 a, float4 b) {
    union { bf16 t[8]; uint4 v; } u;
    u.t[0] = (bf16)a.x; u.t[1] = (bf16)a.y; u.t[2] = (bf16)a.z; u.t[3] = (bf16)a.w;
    u.t[4] = (bf16)b.x; u.t[5] = (bf16)b.y; u.t[6] = (bf16)b.z; u.t[7] = (bf16)b.w;
    return u.v;
}

// ---------------- fused f32 -> bf16 convert for x and W (one launch) ----------------
__global__ void LE_cvt2_kernel(const float* __restrict__ x, const float* __restrict__ w,
                               bf16* __restrict__ out, int nx, int ntot) {
    const int stride = gridDim.x * blockDim.x * 8;
    for (int i = (blockIdx.x * blockDim.x + threadIdx.x) * 8; i < ntot; i += stride) {
        const float* s = (i < nx) ? (x + i) : (w + (i - nx));
        float4 f0 = *(const float4*)s;
        float4 f1 = *(const float4*)(s + 4);
        *(uint4*)(out + i) = pack8(f0, f1);
    }
}

// ---------------- 256x256 deep-pipelined 32x32x16 MFMA GEMM ----------------
// 512 threads = 8 waves (2 row x 4 col), wave owns 128x64 (4x2 tiles of 32x32).
// LDS: ring of 4 K=32 slices, each = A[256][32] + B[256][32] bf16 = 32 KB -> 128 KiB.
// A-frag (32x32x16): lane holds row (l&31), k = (l>>5)*8..+8  => granule g = ks*2+hi.
// Granule stored at position g ^ ((row>>1)&3) (involution; staging pre-swizzles src).
__global__ __launch_bounds__(512, 2) void LE_gemm32_kernel(const bf16* __restrict__ A,
                                                           const bf16* __restrict__ B,
                                                           const float* __restrict__ bias,
                                                           float* __restrict__ out) {
    constexpr int K  = 1024;
    constexpr int NS = 32;                 // K / 32 slices
    __shared__ bf16 As[4][256 * 32];       // 64 KB (slot stride 16384 B)
    __shared__ bf16 Bs[4][256 * 32];       // 64 KB

    // XCD band swizzle: 512 blocks, each XCD gets 16 row-tiles x 4 col-tiles.
    const int raw  = blockIdx.x;
    const int xcd  = raw & 7;
    const int idx  = raw >> 3;             // 0..63
    const int trow = idx >> 2;             // 0..15
    const int tcol = xcd * 4 + (idx & 3);  // 0..31

    const int tid  = threadIdx.x;
    const int lane = tid & 63;
    const int w    = tid >> 6;             // wave 0..7
    const int wr   = w >> 2, wc = w & 3;   // 2 x 4 wave grid
    const int r32  = lane & 31;            // fragment row/col
    const int hi   = lane >> 5;            // k-group
    const int m0   = (lane >> 1) & 1;
    const int m1   = (lane >> 2) & 1;

    const bf16* Ag = A + (size_t)trow * 256 * K;
    const bf16* Bg = B + (size_t)tcol * 256 * K;
    // staging: thread t covers 16 B of row (t>>2) [+128 for 2nd issue];
    // source granule pre-swizzled so the linear LDS write realizes the XOR layout.
    const int sgran = ((tid & 3) ^ ((tid >> 3) & 3)) * 8;
    const bf16* a_src = Ag + (size_t)(tid >> 2) * K + sgran;
    const bf16* b_src = Bg + (size_t)(tid >> 2) * K + sgran;

    // fragment-read bases: granule position for (ks,hi) is (ks^m1)<<1 | (hi^m0)
    const int p0 = (m1 << 1) | (hi ^ m0);  // ks = 0
    const int p1 = p0 ^ 2;                 // ks = 1
    const char* pa0 = (const char*)As + wr * 8192 + r32 * 64 + p0 * 16;
    const char* pa1 = (const char*)As + wr * 8192 + r32 * 64 + p1 * 16;
    const char* pb0 = (const char*)Bs + wc * 4096 + r32 * 64 + p0 * 16;
    const char* pb1 = (const char*)Bs + wc * 4096 + r32 * 64 + p1 * 16;

    f32x16 acc[4][2];
#pragma unroll
    for (int mt = 0; mt < 4; ++mt)
#pragma unroll
        for (int nt = 0; nt < 2; ++nt)
#pragma unroll
            for (int e = 0; e < 16; ++e) acc[mt][nt][e] = 0.f;

    // -------- prologue: stage slices 0,1,2 (12 loads/thread), land slice 0 --------
    for (int js = 0; js < 3; ++js) {
        char* da = (char*)As + js * 16384 + tid * 16;
        char* db = (char*)Bs + js * 16384 + tid * 16;
        const bf16* sa = a_src + js * 32;
        const bf16* sb = b_src + js * 32;
        gload_lds16(da,        sa);
        gload_lds16(da + 8192, sa + (size_t)128 * K);
        gload_lds16(db,        sb);
        gload_lds16(db + 8192, sb + (size_t)128 * K);
    }
    VMCNT(8);          // drain slice 0 (slices 1,2 stay in flight)
    wg_barrier();

#define DO_SLICE(S, JO)                                                                 \
    {                                                                                   \
        constexpr int SOFF = (S) * 16384;                                               \
        constexpr int NOFF = (((S) + 3) & 3) * 16384;                                   \
        const int j = (JO) + (S);                                                       \
        /* issue all 12 fragment reads (ks0 first, then ks1) */                         \
        bf16x8 b00 = ds_read_frag<SOFF + 0>(pb0);                                       \
        bf16x8 b10 = ds_read_frag<SOFF + 2048>(pb0);                                    \
        bf16x8 a00 = ds_read_frag<SOFF + 0>(pa0);                                       \
        bf16x8 a10 = ds_read_frag<SOFF + 2048>(pa0);                                    \
        bf16x8 a20 = ds_read_frag<SOFF + 4096>(pa0);                                    \
        bf16x8 a30 = ds_read_frag<SOFF + 6144>(pa0);                                    \
        if (j < NS - 3) {              /* stage slice j+3 (fire-and-forget, vmcnt) */   \
            char* da = (char*)As + NOFF + tid * 16;                                     \
            char* db = (char*)Bs + NOFF + tid * 16;                                     \
            const bf16* sa = a_src + (j + 3) * 32;                                      \
            const bf16* sb = b_src + (j + 3) * 32;                                      \
            gload_lds16(da,        sa);                                                 \
            gload_lds16(da + 8192, sa + (size_t)128 * K);                               \
            gload_lds16(db,        sb);                                                 \
            gload_lds16(db + 8192, sb + (size_t)128 * K);                               \
        }                                                                               \
        bf16x8 b01 = ds_read_frag<SOFF + 0>(pb1);                                       \
        bf16x8 b11 = ds_read_frag<SOFF + 2048>(pb1);                                    \
        bf16x8 a01 = ds_read_frag<SOFF + 0>(pa1);                                       \
        bf16x8 a11 = ds_read_frag<SOFF + 2048>(pa1);                                    \
        bf16x8 a21 = ds_read_frag<SOFF + 4096>(pa1);                                    \
        bf16x8 a31 = ds_read_frag<SOFF + 6144>(pa1);                                    \
        LGKMCNT(6);                    /* oldest 6 = all ks0 frags (in-order DS) */     \
        SCHED_FENCE();                                                                  \
        __builtin_amdgcn_s_setprio(1);                                                  \
        acc[0][0] = MFMA32(a00, b00, acc[0][0]);                                        \
        acc[0][1] = MFMA32(a00, b10, acc[0][1]);                                        \
        acc[1][0] = MFMA32(a10, b00, acc[1][0]);                                        \
        acc[1][1] = MFMA32(a10, b10, acc[1][1]);                                        \
        acc[2][0] = MFMA32(a20, b00, acc[2][0]);                                        \
        acc[2][1] = MFMA32(a20, b10, acc[2][1]);                                        \
        acc[3][0] = MFMA32(a30, b00, acc[3][0]);                                        \
        acc[3][1] = MFMA32(a30, b10, acc[3][1]);                                        \
        LGKMCNT(0);                    /* ks1 frags landed under the ks0 block */       \
        SCHED_FENCE();                                                                  \
        acc[0][0] = MFMA32(a01, b01, acc[0][0]);                                        \
        acc[0][1] = MFMA32(a01, b11, acc[0][1]);                                        \
        acc[1][0] = MFMA32(a11, b01, acc[1][0]);                                        \
        acc[1][1] = MFMA32(a11, b11, acc[1][1]);                                        \
        acc[2][0] = MFMA32(a21, b01, acc[2][0]);                                        \
        acc[2][1] = MFMA32(a21, b11, acc[2][1]);                                        \
        acc[3][0] = MFMA32(a31, b01, acc[3][0]);                                        \
        acc[3][1] = MFMA32(a31, b11, acc[3][1]);                                        \
        __builtin_amdgcn_s_setprio(0);                                                  \
        SCHED_FENCE();                                                                  \
        /* slice-end sync: per-wave counted guard for slot j+1; barrier globalizes   */ \
        /* it AND licenses staging into slot (j+4)&3.                                */ \
        if (j <= NS - 4)      { VMCNT(8); wg_barrier(); }                               \
        else if (j == NS - 3) { VMCNT(4); wg_barrier(); }                               \
        else if (j == NS - 2) { VMCNT(0); wg_barrier(); }                               \
        /* j == NS-1: fall through to epilogue */                                       \
    }

    for (int jo = 0; jo < NS; jo += 4) {
        DO_SLICE(0, jo);
        DO_SLICE(1, jo);
        DO_SLICE(2, jo);
        DO_SLICE(3, jo);
    }
#undef DO_SLICE

    // ---------------- epilogue: C = acc + bias[col] ----------------
    // C/D 32x32 layout: col = lane&31, row = (reg&3) + 8*(reg>>2) + 4*(lane>>5)
    const int rowb = trow * 256 + wr * 128;
    const int colb = tcol * 256 + wc * 64;
    const int col0 = colb + r32;
    const float bv0 = bias[col0];
    const float bv1 = bias[col0 + 32];
#pragma unroll
    for (int mt = 0; mt < 4; ++mt) {
#pragma unroll
        for (int nt = 0; nt < 2; ++nt) {
            const f32x16 v = acc[mt][nt];
            const float bvv = nt ? bv1 : bv0;
            const int c = col0 + nt * 32;
#pragma unroll
            for (int rg = 0; rg < 4; ++rg) {
                const int r0 = rowb + mt * 32 + rg * 8 + 4 * hi;
                float* p = out + (size_t)r0 * 8192 + c;
                p[0 * 8192] = v[rg * 4 + 0] + bvv;
                p[1 * 8192] = v[rg * 4 + 1] + bvv;
                p[2 * 8192] = v[rg * 4 + 2] + bvv;
                p[3 * 8192] = v[rg * 4 + 3] + bvv;
            }
        }
    }
}

// ---------------- fallback (no workspace): reg-staged f32 128x128 GEMM ----------------
__global__ __launch_bounds__(256) void LE_gemm_fb_kernel(const float* __restrict__ A,
                                                         const float* __restrict__ B,
                                                         const float* __restrict__ bias,
                                                         float* __restrict__ out) {
    constexpr int K = 1024;
    __shared__ bf16 As[128 * 32];
    __shared__ bf16 Bs[128 * 32];

    const int raw  = blockIdx.x;
    const int xcd  = raw & 7;
    const int idx  = raw >> 3;
    const int trow = idx & 31;
    const int tcol = xcd * 8 + (idx >> 5);

    const int tid  = threadIdx.x;
    const int lane = tid & 63;
    const int w    = tid >> 6;
    const int wr   = w >> 1, wc = w & 1;
    const int fr   = lane & 15;
    const int fq   = lane >> 4;

    f32x4 acc[4][4];
    const f32x4 zero = {0.f, 0.f, 0.f, 0.f};
#pragma unroll
    for (int mi = 0; mi < 4; mi++)
#pragma unroll
        for (int ni = 0; ni < 4; ni++) acc[mi][ni] = zero;

    const float* Ap = A + (size_t)trow * 128 * K;
    const float* Bp = B + (size_t)tcol * 128 * K;
    const int sr = tid >> 1;
    const int sc = (tid & 1) * 16;
    for (int k0 = 0; k0 < K; k0 += 32) {
        const float* pa = Ap + (size_t)sr * K + k0 + sc;
        const float* pb = Bp + (size_t)sr * K + k0 + sc;
        float4 a0 = *(const float4*)(pa + 0);
        float4 a1 = *(const float4*)(pa + 4);
        float4 a2 = *(const float4*)(pa + 8);
        float4 a3 = *(const float4*)(pa + 12);
        float4 b0 = *(const float4*)(pb + 0);
        float4 b1 = *(const float4*)(pb + 4);
        float4 b2 = *(const float4*)(pb + 8);
        float4 b3 = *(const float4*)(pb + 12);
        __syncthreads();
        char* la = (char*)As + sr * 64 + sc * 2;
        char* lb = (char*)Bs + sr * 64 + sc * 2;
        *(uint4*)(la)      = pack8(a0, a1);
        *(uint4*)(la + 16) = pack8(a2, a3);
        *(uint4*)(lb)      = pack8(b0, b1);
        *(uint4*)(lb + 16) = pack8(b2, b3);
        __syncthreads();
        bf16x8 af[4], bfv2[4];
#pragma unroll
        for (int mi = 0; mi < 4; mi++)
            af[mi] = *(const bf16x8*)&As[(wr * 64 + mi * 16 + fr) * 32 + fq * 8];
#pragma unroll
        for (int ni = 0; ni < 4; ni++)
            bfv2[ni] = *(const bf16x8*)&Bs[(wc * 64 + ni * 16 + fr) * 32 + fq * 8];
#pragma unroll
        for (int mi = 0; mi < 4; mi++)
#pragma unroll
            for (int ni = 0; ni < 4; ni++)
                acc[mi][ni] = __builtin_amdgcn_mfma_f32_16x16x32_bf16(af[mi], bfv2[ni],
                                                                      acc[mi][ni], 0, 0, 0);
    }
    __syncthreads();

    const int rowb = trow * 128 + wr * 64;
    const int colb = tcol * 128 + wc * 64;
#pragma unroll
    for (int mi = 0; mi < 4; mi++) {
        const int r0 = rowb + mi * 16 + fq * 4;
#pragma unroll
        for (int ni = 0; ni < 4; ni++) {
            const int c = colb + ni * 16 + fr;
            const float bvv = bias[c];
            float* p = out + (size_t)r0 * 8192 + c;
            f32x4 v = acc[mi][ni];
            p[0 * 8192] = v[0] + bvv;
            p[1 * 8192] = v[1] + bvv;
            p[2 * 8192] = v[2] + bvv;
            p[3 * 8192] = v[3] + bvv;
        }
    }
}

extern "C" void kernel_launch(void* const* d_in, const int* in_sizes, int n_in,
                              void* d_out, int out_size, void* d_ws, size_t ws_size,
                              hipStream_t stream) {
    const float* x    = (const float*)d_in[0];   // [4096, 1024]
    const float* wgt  = (const float*)d_in[1];   // [8, 1024, 1024] == Wbig^T [8192,1024]
    const float* bias = (const float*)d_in[2];   // [8, 1024] == [8192]
    float* out = (float*)d_out;                  // [4096, 8192]

    const size_t NX = (size_t)4096 * 1024;
    const size_t NW = (size_t)8192 * 1024;

    if (ws_size >= (NX + NW) * sizeof(bf16)) {
        bf16* xb = (bf16*)d_ws;
        bf16* wb = xb + NX;
        LE_cvt2_kernel<<<2048, 256, 0, stream>>>(x, wgt, xb, (int)NX, (int)(NX + NW));
        LE_gemm32_kernel<<<512, 512, 0, stream>>>(xb, wb, bias, out);
    } else {
        LE_gemm_fb_kernel<<<2048, 256, 0, stream>>>(x, wgt, bias, out);
    }
}

// Round 7
// 95.887 us; speedup vs baseline: 1.0032x; 1.0032x over previous
//
#include <hip/hip_runtime.h>
#include <hip/hip_bf16.h>
#include <stdint.h>

// LinearEnsemble: out[b,m,o] = sum_i W[m,o,i]*x[b,i] + bias[m,o]
// == C[4096x8192] = x[4096x1024] * Wbig^T (+bias), Wbig = [8192x1024] row-major.
// v8: v6 structure EXACTLY (last passing kernel) + corrected granule swizzle only.
//     sw(r) = ((r>>1)&3) ^ ((r>>3)&3)  [v6's ((r>>1)&3) left lanes l,l+16 on the
//     same banks -> measured exactly 4 conflict-units/read]. Both-sides involution:
//     staging pre-swizzles the global source granule; reads apply the same XOR.
//     v7's reg-double-buffer pipeline is quarantined (NaN, suspected spill-induced
//     vmcnt corruption); re-introduce incrementally on a green base.

typedef __bf16 bf16;
typedef __attribute__((ext_vector_type(8))) __bf16 bf16x8;
typedef __attribute__((ext_vector_type(4))) float f32x4;
typedef __attribute__((ext_vector_type(16))) float f32x16;

#define GAS __attribute__((address_space(1)))
#define LAS __attribute__((address_space(3)))

__device__ __forceinline__ void gload_lds16(void* lds, const void* g) {
    __builtin_amdgcn_global_load_lds((const GAS uint32_t*)g, (LAS uint32_t*)lds, 16, 0, 0);
}

// raw barrier with compiler-level memory fence (no vmcnt/lgkm drain emitted)
__device__ __forceinline__ void wg_barrier() {
    asm volatile("" ::: "memory");
    __builtin_amdgcn_s_barrier();
    asm volatile("" ::: "memory");
}

#define VMCNT(n)   asm volatile("s_waitcnt vmcnt(" #n ")" ::: "memory")
#define LGKMCNT(n) asm volatile("s_waitcnt lgkmcnt(" #n ")" ::: "memory")
#define SCHED_FENCE() __builtin_amdgcn_sched_barrier(0)

// untracked LDS fragment read; ordering enforced by waits + SCHED_FENCE (rule 18)
template<int OFF>
__device__ __forceinline__ bf16x8 ds_read_frag(const char* p) {
    f32x4 r;
    asm volatile("ds_read_b128 %0, %1 offset:%2"
                 : "=v"(r)
                 : "v"((const LAS char*)p), "i"(OFF));
    return __builtin_bit_cast(bf16x8, r);
}

#define MFMA32(A, B, C) __builtin_amdgcn_mfma_f32_32x32x16_bf16(A, B, C, 0, 0, 0)

__device__ __forceinline__ uint4 pack8(float4 a, float4 b) {
    union { bf16 t[8]; uint4 v; } u;
    u.t[0] = (bf16)a.x; u.t[1] = (bf16)a.y; u.t[2] = (bf16)a.z; u.t[3] = (bf16)a.w;
    u.t[4] = (bf16)b.x; u.t[5] = (bf16)b.y; u.t[6] = (bf16)b.z; u.t[7] = (bf16)b.w;
    return u.v;
}

// ---------------- fused f32 -> bf16 convert for x and W (one launch) ----------------
__global__ void LE_cvt2_kernel(const float* __restrict__ x, const float* __restrict__ w,
                               bf16* __restrict__ out, int nx, int ntot) {
    const int stride = gridDim.x * blockDim.x * 8;
    for (int i = (blockIdx.x * blockDim.x + threadIdx.x) * 8; i < ntot; i += stride) {
        const float* s = (i < nx) ? (x + i) : (w + (i - nx));
        float4 f0 = *(const float4*)s;
        float4 f1 = *(const float4*)(s + 4);
        *(uint4*)(out + i) = pack8(f0, f1);
    }
}

// ---------------- 256x256 deep-pipelined 32x32x16 MFMA GEMM ----------------
// 512 threads = 8 waves (2 row x 4 col), wave owns 128x64 (4x2 tiles of 32x32).
// LDS: ring of 4 K=32 slices, each = A[256][32] + B[256][32] bf16 = 32 KB -> 128 KiB.
// A-frag (32x32x16): lane holds row (l&31), k = ks*16 + (l>>5)*8 .. +8
//   => logical granule g = ks*2 + hi, stored at position g ^ sw(row),
//      sw(r) = ((r>>1)&3) ^ ((r>>3)&3).
__global__ __launch_bounds__(512, 2) void LE_gemm32_kernel(const bf16* __restrict__ A,
                                                           const bf16* __restrict__ B,
                                                           const float* __restrict__ bias,
                                                           float* __restrict__ out) {
    constexpr int K  = 1024;
    constexpr int NS = 32;                 // K / 32 slices
    __shared__ bf16 As[4][256 * 32];       // 64 KB (slot stride 16384 B)
    __shared__ bf16 Bs[4][256 * 32];       // 64 KB

    // XCD band swizzle: 512 blocks, each XCD gets 16 row-tiles x 4 col-tiles.
    const int raw  = blockIdx.x;
    const int xcd  = raw & 7;
    const int idx  = raw >> 3;             // 0..63
    const int trow = idx >> 2;             // 0..15
    const int tcol = xcd * 4 + (idx & 3);  // 0..31

    const int tid  = threadIdx.x;
    const int lane = tid & 63;
    const int w    = tid >> 6;             // wave 0..7
    const int wr   = w >> 2, wc = w & 3;   // 2 x 4 wave grid
    const int r32  = lane & 31;            // fragment row/col
    const int hi   = lane >> 5;            // k-group

    const bf16* Ag = A + (size_t)trow * 256 * K;
    const bf16* Bg = B + (size_t)tcol * 256 * K;
    // staging: thread t covers 16 B of row (t>>2) [+128 for 2nd issue].
    // Stored pos s = t&3 must hold logical granule s ^ sw(row), row = t>>2:
    // sw bits from tid: ((tid>>3)&3) ^ ((tid>>5)&3).
    const int sgran = ((tid & 3) ^ ((tid >> 3) & 3) ^ ((tid >> 5) & 3)) * 8;
    const bf16* a_src = Ag + (size_t)(tid >> 2) * K + sgran;
    const bf16* b_src = Bg + (size_t)(tid >> 2) * K + sgran;

    // fragment-read bases: position for (ks,hi) = (ks*2+hi) ^ sw(r32).
    // All tile row-offsets (+32/+64/+96) and B's +32 preserve sw (bits 1-4 only).
    const int sw = ((lane >> 1) & 3) ^ ((lane >> 3) & 3);
    const int p0 = hi ^ sw;                // ks = 0
    const int p1 = p0 ^ 2;                 // ks = 1
    const char* pa0 = (const char*)As + wr * 8192 + r32 * 64 + p0 * 16;
    const char* pa1 = (const char*)As + wr * 8192 + r32 * 64 + p1 * 16;
    const char* pb0 = (const char*)Bs + wc * 4096 + r32 * 64 + p0 * 16;
    const char* pb1 = (const char*)Bs + wc * 4096 + r32 * 64 + p1 * 16;

    f32x16 acc[4][2];
#pragma unroll
    for (int mt = 0; mt < 4; ++mt)
#pragma unroll
        for (int nt = 0; nt < 2; ++nt)
#pragma unroll
            for (int e = 0; e < 16; ++e) acc[mt][nt][e] = 0.f;

    // -------- prologue: stage slices 0,1,2 (12 loads/thread), land slice 0 --------
    for (int js = 0; js < 3; ++js) {
        char* da = (char*)As + js * 16384 + tid * 16;
        char* db = (char*)Bs + js * 16384 + tid * 16;
        const bf16* sa = a_src + js * 32;
        const bf16* sb = b_src + js * 32;
        gload_lds16(da,        sa);
        gload_lds16(da + 8192, sa + (size_t)128 * K);
        gload_lds16(db,        sb);
        gload_lds16(db + 8192, sb + (size_t)128 * K);
    }
    VMCNT(8);          // drain slice 0 (slices 1,2 stay in flight)
    wg_barrier();

#define DO_SLICE(S, JO)                                                                 \
    {                                                                                   \
        constexpr int SOFF = (S) * 16384;                                               \
        constexpr int NOFF = (((S) + 3) & 3) * 16384;                                   \
        const int j = (JO) + (S);                                                       \
        /* issue all 12 fragment reads (ks0 first, then ks1) */                         \
        bf16x8 b00 = ds_read_frag<SOFF + 0>(pb0);                                       \
        bf16x8 b10 = ds_read_frag<SOFF + 2048>(pb0);                                    \
        bf16x8 a00 = ds_read_frag<SOFF + 0>(pa0);                                       \
        bf16x8 a10 = ds_read_frag<SOFF + 2048>(pa0);                                    \
        bf16x8 a20 = ds_read_frag<SOFF + 4096>(pa0);                                    \
        bf16x8 a30 = ds_read_frag<SOFF + 6144>(pa0);                                    \
        if (j < NS - 3) {              /* stage slice j+3 (fire-and-forget, vmcnt) */   \
            char* da = (char*)As + NOFF + tid * 16;                                     \
            char* db = (char*)Bs + NOFF + tid * 16;                                     \
            const bf16* sa = a_src + (j + 3) * 32;                                      \
            const bf16* sb = b_src + (j + 3) * 32;                                      \
            gload_lds16(da,        sa);                                                 \
            gload_lds16(da + 8192, sa + (size_t)128 * K);                               \
            gload_lds16(db,        sb);                                                 \
            gload_lds16(db + 8192, sb + (size_t)128 * K);                               \
        }                                                                               \
        bf16x8 b01 = ds_read_frag<SOFF + 0>(pb1);                                       \
        bf16x8 b11 = ds_read_frag<SOFF + 2048>(pb1);                                    \
        bf16x8 a01 = ds_read_frag<SOFF + 0>(pa1);                                       \
        bf16x8 a11 = ds_read_frag<SOFF + 2048>(pa1);                                    \
        bf16x8 a21 = ds_read_frag<SOFF + 4096>(pa1);                                    \
        bf16x8 a31 = ds_read_frag<SOFF + 6144>(pa1);                                    \
        LGKMCNT(6);                    /* oldest 6 = all ks0 frags (in-order DS) */     \
        SCHED_FENCE();                                                                  \
        __builtin_amdgcn_s_setprio(1);                                                  \
        acc[0][0] = MFMA32(a00, b00, acc[0][0]);                                        \
        acc[0][1] = MFMA32(a00, b10, acc[0][1]);                                        \
        acc[1][0] = MFMA32(a10, b00, acc[1][0]);                                        \
        acc[1][1] = MFMA32(a10, b10, acc[1][1]);                                        \
        acc[2][0] = MFMA32(a20, b00, acc[2][0]);                                        \
        acc[2][1] = MFMA32(a20, b10, acc[2][1]);                                        \
        acc[3][0] = MFMA32(a30, b00, acc[3][0]);                                        \
        acc[3][1] = MFMA32(a30, b10, acc[3][1]);                                        \
        LGKMCNT(0);                    /* ks1 frags landed under the ks0 block */       \
        SCHED_FENCE();                                                                  \
        acc[0][0] = MFMA32(a01, b01, acc[0][0]);                                        \
        acc[0][1] = MFMA32(a01, b11, acc[0][1]);                                        \
        acc[1][0] = MFMA32(a11, b01, acc[1][0]);                                        \
        acc[1][1] = MFMA32(a11, b11, acc[1][1]);                                        \
        acc[2][0] = MFMA32(a21, b01, acc[2][0]);                                        \
        acc[2][1] = MFMA32(a21, b11, acc[2][1]);                                        \
        acc[3][0] = MFMA32(a31, b01, acc[3][0]);                                        \
        acc[3][1] = MFMA32(a31, b11, acc[3][1]);                                        \
        __builtin_amdgcn_s_setprio(0);                                                  \
        SCHED_FENCE();                                                                  \
        /* slice-end sync: per-wave counted guard for slot j+1; barrier globalizes   */ \
        /* it AND licenses staging into slot (j+4)&3.                                */ \
        if (j <= NS - 4)      { VMCNT(8); wg_barrier(); }                               \
        else if (j == NS - 3) { VMCNT(4); wg_barrier(); }                               \
        else if (j == NS - 2) { VMCNT(0); wg_barrier(); }                               \
        /* j == NS-1: fall through to epilogue */                                       \
    }

    for (int jo = 0; jo < NS; jo += 4) {
        DO_SLICE(0, jo);
        DO_SLICE(1, jo);
        DO_SLICE(2, jo);
        DO_SLICE(3, jo);
    }
#undef DO_SLICE

    // ---------------- epilogue: C = acc + bias[col] ----------------
    // C/D 32x32 layout: col = lane&31, row = (reg&3) + 8*(reg>>2) + 4*(lane>>5)
    const int rowb = trow * 256 + wr * 128;
    const int colb = tcol * 256 + wc * 64;
    const int col0 = colb + r32;
    const float bv0 = bias[col0];
    const float bv1 = bias[col0 + 32];
#pragma unroll
    for (int mt = 0; mt < 4; ++mt) {
#pragma unroll
        for (int nt = 0; nt < 2; ++nt) {
            const f32x16 v = acc[mt][nt];
            const float bvv = nt ? bv1 : bv0;
            const int c = col0 + nt * 32;
#pragma unroll
            for (int rg = 0; rg < 4; ++rg) {
                const int r0 = rowb + mt * 32 + rg * 8 + 4 * hi;
                float* p = out + (size_t)r0 * 8192 + c;
                p[0 * 8192] = v[rg * 4 + 0] + bvv;
                p[1 * 8192] = v[rg * 4 + 1] + bvv;
                p[2 * 8192] = v[rg * 4 + 2] + bvv;
                p[3 * 8192] = v[rg * 4 + 3] + bvv;
            }
        }
    }
}

// ---------------- fallback (no workspace): reg-staged f32 128x128 GEMM ----------------
__global__ __launch_bounds__(256) void LE_gemm_fb_kernel(const float* __restrict__ A,
                                                         const float* __restrict__ B,
                                                         const float* __restrict__ bias,
                                                         float* __restrict__ out) {
    constexpr int K = 1024;
    __shared__ bf16 As[128 * 32];
    __shared__ bf16 Bs[128 * 32];

    const int raw  = blockIdx.x;
    const int xcd  = raw & 7;
    const int idx  = raw >> 3;
    const int trow = idx & 31;
    const int tcol = xcd * 8 + (idx >> 5);

    const int tid  = threadIdx.x;
    const int lane = tid & 63;
    const int w    = tid >> 6;
    const int wr   = w >> 1, wc = w & 1;
    const int fr   = lane & 15;
    const int fq   = lane >> 4;

    f32x4 acc[4][4];
    const f32x4 zero = {0.f, 0.f, 0.f, 0.f};
#pragma unroll
    for (int mi = 0; mi < 4; mi++)
#pragma unroll
        for (int ni = 0; ni < 4; ni++) acc[mi][ni] = zero;

    const float* Ap = A + (size_t)trow * 128 * K;
    const float* Bp = B + (size_t)tcol * 128 * K;
    const int sr = tid >> 1;
    const int sc = (tid & 1) * 16;
    for (int k0 = 0; k0 < K; k0 += 32) {
        const float* pa = Ap + (size_t)sr * K + k0 + sc;
        const float* pb = Bp + (size_t)sr * K + k0 + sc;
        float4 a0 = *(const float4*)(pa + 0);
        float4 a1 = *(const float4*)(pa + 4);
        float4 a2 = *(const float4*)(pa + 8);
        float4 a3 = *(const float4*)(pa + 12);
        float4 b0 = *(const float4*)(pb + 0);
        float4 b1 = *(const float4*)(pb + 4);
        float4 b2 = *(const float4*)(pb + 8);
        float4 b3 = *(const float4*)(pb + 12);
        __syncthreads();
        char* la = (char*)As + sr * 64 + sc * 2;
        char* lb = (char*)Bs + sr * 64 + sc * 2;
        *(uint4*)(la)      = pack8(a0, a1);
        *(uint4*)(la + 16) = pack8(a2, a3);
        *(uint4*)(lb)      = pack8(b0, b1);
        *(uint4*)(lb + 16) = pack8(b2, b3);
        __syncthreads();
        bf16x8 af[4], bfv2[4];
#pragma unroll
        for (int mi = 0; mi < 4; mi++)
            af[mi] = *(const bf16x8*)&As[(wr * 64 + mi * 16 + fr) * 32 + fq * 8];
#pragma unroll
        for (int ni = 0; ni < 4; ni++)
            bfv2[ni] = *(const bf16x8*)&Bs[(wc * 64 + ni * 16 + fr) * 32 + fq * 8];
#pragma unroll
        for (int mi = 0; mi < 4; mi++)
#pragma unroll
            for (int ni = 0; ni < 4; ni++)
                acc[mi][ni] = __builtin_amdgcn_mfma_f32_16x16x32_bf16(af[mi], bfv2[ni],
                                                                      acc[mi][ni], 0, 0, 0);
    }
    __syncthreads();

    const int rowb = trow * 128 + wr * 64;
    const int colb = tcol * 128 + wc * 64;
#pragma unroll
    for (int mi = 0; mi < 4; mi++) {
        const int r0 = rowb + mi * 16 + fq * 4;
#pragma unroll
        for (int ni = 0; ni < 4; ni++) {
            const int c = colb + ni * 16 + fr;
            const float bvv = bias[c];
            float* p = out + (size_t)r0 * 8192 + c;
            f32x4 v = acc[mi][ni];
            p[0 * 8192] = v[0] + bvv;
            p[1 * 8192] = v[1] + bvv;
            p[2 * 8192] = v[2] + bvv;
            p[3 * 8192] = v[3] + bvv;
        }
    }
}

extern "C" void kernel_launch(void* const* d_in, const int* in_sizes, int n_in,
                              void* d_out, int out_size, void* d_ws, size_t ws_size,
                              hipStream_t stream) {
    const float* x    = (const float*)d_in[0];   // [4096, 1024]
    const float* wgt  = (const float*)d_in[1];   // [8, 1024, 1024] == Wbig^T [8192,1024]
    const float* bias = (const float*)d_in[2];   // [8, 1024] == [8192]
    float* out = (float*)d_out;                  // [4096, 8192]

    const size_t NX = (size_t)4096 * 1024;
    const size_t NW = (size_t)8192 * 1024;

    if (ws_size >= (NX + NW) * sizeof(bf16)) {
        bf16* xb = (bf16*)d_ws;
        bf16* wb = xb + NX;
        LE_cvt2_kernel<<<2048, 256, 0, stream>>>(x, wgt, xb, (int)NX, (int)(NX + NW));
        LE_gemm32_kernel<<<512, 512, 0, stream>>>(xb, wb, bias, out);
    } else {
        LE_gemm_fb_kernel<<<2048, 256, 0, stream>>>(x, wgt, bias, out);
    }
}